// Round 2
// baseline (182.796 us; speedup 1.0000x reference)
//
#include <hip/hip_runtime.h>

typedef __attribute__((ext_vector_type(8))) __bf16 bf16x8;
typedef __attribute__((ext_vector_type(4))) float f32x4;
typedef __attribute__((ext_vector_type(8))) unsigned short ushort8;

#define DSAMP 512
#define DIM   128
#define REG5  16384                // one staged region: 128 rows * 128 B (bf16, swizzled)
#define NPAIR 18                   // paired tiles per batch (2 tiles per block)

// ---------------------------------------------------------------------------
// Single-pass fused kernel. Each block owns one A row-panel of one batch and
// computes TWO 128x128 distance tiles against it. fp32 panels are loaded
// directly from x/y (no presplit pass), converted to bf16-hi (RNE) in
// registers, ds_written into the swizzled LDS layout; exact fp32 row norms
// are computed in-flight with the same reduction tree as the old presplit.
// B-chunk staging is split issue-early/write-late (T14) so the global-load
// latency hides under the MFMA phases. Blocks of one batch are
// dispatch-adjacent within one XCD (bid%8 = batch%8) so fp32 re-reads are
// L2-resident (~2.7 MB hot per XCD).
// Pair schedule (verified in R0): 16 xy + 10 xx + 10 yy tiles balanced into
// 18 pairs sharing an A panel; diagonal sub-tile always in slot 0.
// ---------------------------------------------------------------------------
__constant__ unsigned char T_Asrc[NPAIR]  = {0,0,0,0,0,0,0,0, 1,1,1,1,1,1,1,1,1,1};
__constant__ unsigned char T_Ai[NPAIR]    = {0,0,1,1,1,2,2,3, 0,0,0,0,1,1,1,2,2,3};
__constant__ unsigned char T_Bsrc0[NPAIR] = {0,0,0,0,1,0,1,0, 1,1,0,0,1,1,0,1,0,1};
__constant__ unsigned char T_Bsrc1[NPAIR] = {0,0,0,1,1,0,1,1, 1,1,0,0,1,0,0,1,0,0};
__constant__ unsigned char T_Bj0[NPAIR]   = {0,2,1,3,2,2,2,3, 0,2,0,2,1,3,2,2,0,3};
__constant__ unsigned char T_Bj1[NPAIR]   = {1,3,2,1,3,3,3,3, 1,3,1,3,2,0,3,3,3,0};
// weight codes: 0 -> +1.0 (xy), 1 -> -1.0 (xx/yy off-diag), 2 -> -0.5 (diag)
__constant__ char          T_wc0[NPAIR]   = {2,1,2,1,0,2,0,2, 2,1,0,0,2,1,0,2,0,2};
__constant__ char          T_wc1[NPAIR]   = {1,1,1,0,0,1,0,0, 1,1,0,0,1,0,0,1,0,0};
__constant__ unsigned char T_d0[NPAIR]    = {1,0,1,0,0,1,0,1, 1,0,0,0,1,0,0,1,0,1};

__global__ __launch_bounds__(256, 3)
void mmd_fused(const float* __restrict__ x, const float* __restrict__ y,
               float* __restrict__ partials) {
    __shared__ __align__(16) char smem[3 * REG5];   // A c0 | A c1 | B (49152 B)
    __shared__ float Pn[128];
    __shared__ float Qn0[128];
    __shared__ float Qn1[128];
    __shared__ float wred[4];

    const int tid = threadIdx.x;
    const int bid = blockIdx.x;
    const int xcd = bid & 7;
    const int seq = bid >> 3;            // 0..287
    const int s   = seq % NPAIR;
    const int grp = seq / NPAIR;         // 0..15
    const int b   = xcd + 8 * grp;       // batch; all 18 pair-blocks adjacent

    const int Ai  = T_Ai[s];
    const int Bj0 = T_Bj0[s];
    const int Bj1 = T_Bj1[s];
    const float* Asrc  = T_Asrc[s]  ? y : x;
    const float* B0src = T_Bsrc0[s] ? y : x;
    const float* B1src = T_Bsrc1[s] ? y : x;
    const int wc0 = T_wc0[s], wc1 = T_wc1[s];
    const float w0 = (wc0 == 0) ? 1.0f : ((wc0 == 1) ? -1.0f : -0.5f);
    const float w1 = (wc1 == 0) ? 1.0f : ((wc1 == 1) ? -1.0f : -0.5f);
    const bool dg0 = T_d0[s] != 0;

    const size_t rowbase = (size_t)b * 512;
    const float* Ap  = Asrc  + (rowbase + (size_t)Ai  * 128) * 128;
    const float* Bp0 = B0src + (rowbase + (size_t)Bj0 * 128) * 128;
    const float* Bp1 = B1src + (rowbase + (size_t)Bj1 * 128) * 128;

    const int lane    = tid & 63;
    const int wv      = tid >> 6;
    const int rowHalf = (wv >> 1) * 64;
    const int colHalf = (wv & 1) * 64;
    const int fm      = lane & 15;
    const int kq      = lane >> 4;
    const int sw      = fm & 7;

    // convert 8 fp32 -> bf16-hi (RNE), write 16 B to LDS, return sum of squares
    auto cvt_write16 = [&](float4 v0, float4 v1, char* dst) -> float {
        float xs[8] = {v0.x, v0.y, v0.z, v0.w, v1.x, v1.y, v1.z, v1.w};
        ushort8 hv;
        float ss = 0.f;
        #pragma unroll
        for (int e = 0; e < 8; ++e) {
            ss += xs[e] * xs[e];
            unsigned ub = __float_as_uint(xs[e]);
            hv[e] = (unsigned short)((ub + 0x7fffu + ((ub >> 16) & 1u)) >> 16);
        }
        *(ushort8*)dst = hv;
        return ss;
    };

    // issue the 8 global loads for one B chunk (kept in regs across a phase)
    auto loadB = [&](const float* Bp, int cc, float4 (*vb)[2]) {
        #pragma unroll
        for (int it = 0; it < 4; ++it) {
            int u  = it * 256 + tid;          // (row 0..127, jb 0..7)
            int jb = u & 7;
            int r  = u >> 3;
            const float* g = Bp + (size_t)r * 128 + cc * 64 + jb * 8;
            vb[it][0] = ((const float4*)g)[0];
            vb[it][1] = ((const float4*)g)[1];
        }
    };
    // convert + write one B chunk to LDS, accumulate chunk norm partial
    auto writeB = [&](float4 (*vb)[2], float* Qn, bool add) {
        #pragma unroll
        for (int it = 0; it < 4; ++it) {
            int u  = it * 256 + tid;
            int jb = u & 7;
            int r  = u >> 3;
            float ss = cvt_write16(vb[it][0], vb[it][1],
                                   smem + 2 * REG5 + r * 128 + ((jb ^ (r & 7)) * 16));
            #pragma unroll
            for (int o = 4; o > 0; o >>= 1) ss += __shfl_down(ss, o, 8);
            if ((tid & 7) == 0) { if (add) Qn[r] += ss; else Qn[r] = ss; }
        }
    };

    f32x4 acc[4][4];
    auto zero_acc = [&]() {
        #pragma unroll
        for (int a2 = 0; a2 < 4; ++a2)
            #pragma unroll
            for (int b2 = 0; b2 < 4; ++b2)
                acc[a2][b2] = (f32x4){0.f, 0.f, 0.f, 0.f};
    };

    auto compute = [&](int creg) {
        const char* Ab = smem + creg * REG5;
        const char* Bb = smem + 2 * REG5;
        #pragma unroll
        for (int ks = 0; ks < 2; ++ks) {
            const int jx = ((ks * 4 + kq) ^ sw) * 16;
            bf16x8 ah[4], bh[4];
            #pragma unroll
            for (int a2 = 0; a2 < 4; ++a2)
                ah[a2] = *(const bf16x8*)(Ab + (rowHalf + a2 * 16 + fm) * 128 + jx);
            #pragma unroll
            for (int b2 = 0; b2 < 4; ++b2)
                bh[b2] = *(const bf16x8*)(Bb + (colHalf + b2 * 16 + fm) * 128 + jx);
            __builtin_amdgcn_s_setprio(1);
            #pragma unroll
            for (int a2 = 0; a2 < 4; ++a2)
                #pragma unroll
                for (int b2 = 0; b2 < 4; ++b2)
                    acc[a2][b2] = __builtin_amdgcn_mfma_f32_16x16x32_bf16(
                        ah[a2], bh[b2], acc[a2][b2], 0, 0, 0);
            __builtin_amdgcn_s_setprio(0);
        }
    };

    auto tile_sum = [&](const float* Qn, bool dg) -> float {
        float Pr[16], Qc[4];
        #pragma unroll
        for (int a2 = 0; a2 < 4; ++a2)
            #pragma unroll
            for (int rg2 = 0; rg2 < 4; ++rg2)
                Pr[a2 * 4 + rg2] = Pn[rowHalf + a2 * 16 + kq * 4 + rg2];
        #pragma unroll
        for (int b2 = 0; b2 < 4; ++b2) Qc[b2] = Qn[colHalf + b2 * 16 + fm];
        float ls = 0.f;
        if (dg) {
            #pragma unroll
            for (int a2 = 0; a2 < 4; ++a2)
                #pragma unroll
                for (int b2 = 0; b2 < 4; ++b2)
                    #pragma unroll
                    for (int rg2 = 0; rg2 < 4; ++rg2) {
                        float d2 = fmaf(-2.0f, acc[a2][b2][rg2], Pr[a2 * 4 + rg2] + Qc[b2]);
                        float v  = __builtin_amdgcn_sqrtf(fmaxf(d2, 0.0f));
                        if ((rowHalf + a2 * 16 + kq * 4 + rg2) == (colHalf + b2 * 16 + fm)) v = 0.f;
                        ls += v;
                    }
        } else {
            #pragma unroll
            for (int a2 = 0; a2 < 4; ++a2)
                #pragma unroll
                for (int b2 = 0; b2 < 4; ++b2)
                    #pragma unroll
                    for (int rg2 = 0; rg2 < 4; ++rg2) {
                        float d2 = fmaf(-2.0f, acc[a2][b2][rg2], Pr[a2 * 4 + rg2] + Qc[b2]);
                        ls += __builtin_amdgcn_sqrtf(fmaxf(d2, 0.0f));
                    }
        }
        return ls;
    };

    // ---- phase S: stage A (both chunks) + B0 chunk0; norms for both ----
    {
        float4 va[8][2];
        #pragma unroll
        for (int it = 0; it < 8; ++it) {
            int u  = it * 256 + tid;          // (row, c, jb)
            int jb = u & 7;
            int cc = (u >> 3) & 1;
            int r  = u >> 4;
            const float* g = Ap + (size_t)r * 128 + cc * 64 + jb * 8;
            va[it][0] = ((const float4*)g)[0];
            va[it][1] = ((const float4*)g)[1];
        }
        float4 vb0[4][2];
        loadB(Bp0, 0, vb0);
        #pragma unroll
        for (int it = 0; it < 8; ++it) {
            int u  = it * 256 + tid;
            int jb = u & 7;
            int cc = (u >> 3) & 1;
            int r  = u >> 4;
            float ss = cvt_write16(va[it][0], va[it][1],
                                   smem + cc * REG5 + r * 128 + ((jb ^ (r & 7)) * 16));
            // full-row norm: 16 lanes = (c0 jb0..7, c1 jb0..7) — same tree as presplit
            #pragma unroll
            for (int o = 8; o > 0; o >>= 1) ss += __shfl_down(ss, o, 16);
            if ((tid & 15) == 0) Pn[r] = ss;
        }
        writeB(vb0, Qn0, false);
    }
    __syncthreads();                       // A + B(t0,c0) staged, Pn/Qn0(c0) ready

    // ---- tile 0 ----
    zero_acc();
    float4 vb1[4][2];
    loadB(Bp0, 1, vb1);                    // issue-early: latency under compute
    compute(0);
    __syncthreads();                       // B buf free
    writeB(vb1, Qn0, true);                // Qn0 complete
    __syncthreads();                       // B(t0,c1) staged
    float4 vb2[4][2];
    loadB(Bp1, 0, vb2);
    compute(1);
    float lsum = w0 * tile_sum(Qn0, dg0);  // epilogue overlaps other blocks' work
    zero_acc();
    __syncthreads();                       // B buf free
    writeB(vb2, Qn1, false);
    __syncthreads();                       // B(t1,c0) staged

    // ---- tile 1 ----
    float4 vb3[4][2];
    loadB(Bp1, 1, vb3);
    compute(0);
    __syncthreads();                       // B buf free
    writeB(vb3, Qn1, true);                // Qn1 complete
    __syncthreads();                       // B(t1,c1) staged
    compute(1);
    lsum += w1 * tile_sum(Qn1, false);

    #pragma unroll
    for (int off = 32; off > 0; off >>= 1) lsum += __shfl_down(lsum, off, 64);
    if (lane == 0) wred[wv] = lsum;
    __syncthreads();
    if (tid == 0)
        partials[bid] = wred[0] + wred[1] + wred[2] + wred[3];
}

// ---------------------------------------------------------------------------
// Fallback (in-kernel 3-term conversion, full 48 tiles/batch) if ws too small
// or B != 128.
// ---------------------------------------------------------------------------
__global__ __launch_bounds__(256, 2)
void mmd_tile_fallback(const float* __restrict__ x, const float* __restrict__ y,
                       float* __restrict__ partials) {
    __shared__ __align__(16) char smem[4 * 128 * 144];
    __shared__ float Pn[128];
    __shared__ float Qn[128];
    __shared__ float wred[4];

    char* Ah = smem;
    char* Al = smem + 1 * 128 * 144;
    char* Bh = smem + 2 * 128 * 144;
    char* Bl = smem + 3 * 128 * 144;

    const int tid  = threadIdx.x;
    const int bid  = blockIdx.x;
    const int tj   = bid & 3;
    const int ti   = (bid >> 2) & 3;
    const int type = (bid >> 4) % 3;
    const int b    = bid / 48;

    const float* Xb = x + (size_t)b * DSAMP * DIM;
    const float* Yb = y + (size_t)b * DSAMP * DIM;
    const float* Pp; const float* Qp; float w;
    if (type == 0)      { Pp = Xb; Qp = Yb; w = 1.0f;  }
    else if (type == 1) { Pp = Xb; Qp = Xb; w = -0.5f; }
    else                { Pp = Yb; Qp = Yb; w = -0.5f; }
    Pp += (size_t)ti * 128 * DIM;
    Qp += (size_t)tj * 128 * DIM;

    {
        const float* rp = (tid < 128) ? (Pp + (size_t)tid * DIM)
                                      : (Qp + (size_t)(tid - 128) * DIM);
        float s = 0.f;
        #pragma unroll
        for (int k4 = 0; k4 < 32; ++k4) {
            float4 v = ((const float4*)rp)[k4];
            s += v.x * v.x + v.y * v.y + v.z * v.z + v.w * v.w;
        }
        if (tid < 128) Pn[tid] = s; else Qn[tid - 128] = s;
    }

    const int lane    = tid & 63;
    const int wv      = tid >> 6;
    const int rowHalf = (wv >> 1) * 64;
    const int colHalf = (wv & 1) * 64;
    const int fm      = lane & 15;
    const int kq      = lane >> 4;

    f32x4 acc[4][4];
    #pragma unroll
    for (int a2 = 0; a2 < 4; ++a2)
        #pragma unroll
        for (int b2 = 0; b2 < 4; ++b2)
            acc[a2][b2] = (f32x4){0.f, 0.f, 0.f, 0.f};

    for (int c = 0; c < 2; ++c) {
        if (c) __syncthreads();
        #pragma unroll
        for (int side = 0; side < 2; ++side) {
            const float* sp = side ? Qp : Pp;
            char* dh = side ? Bh : Ah;
            char* dl = side ? Bl : Al;
            #pragma unroll
            for (int it = 0; it < 4; ++it) {
                int u  = it * 256 + tid;
                int r  = u >> 3;
                int c8 = u & 7;
                const float* g = sp + (size_t)r * DIM + c * 64 + c8 * 8;
                float4 v0 = ((const float4*)g)[0];
                float4 v1 = ((const float4*)g)[1];
                float xs[8] = {v0.x, v0.y, v0.z, v0.w, v1.x, v1.y, v1.z, v1.w};
                ushort8 hv, lv;
                #pragma unroll
                for (int e = 0; e < 8; ++e) {
                    float xv = xs[e];
                    unsigned ub = __float_as_uint(xv);
                    unsigned hr = (ub + 0x7fffu + ((ub >> 16) & 1u)) >> 16;
                    float hf = __uint_as_float(hr << 16);
                    float rs = xv - hf;
                    unsigned ul = __float_as_uint(rs);
                    unsigned lr = (ul + 0x7fffu + ((ul >> 16) & 1u)) >> 16;
                    hv[e] = (unsigned short)hr;
                    lv[e] = (unsigned short)lr;
                }
                *(ushort8*)(dh + r * 144 + c8 * 16) = hv;
                *(ushort8*)(dl + r * 144 + c8 * 16) = lv;
            }
        }
        __syncthreads();
        #pragma unroll
        for (int ks = 0; ks < 2; ++ks) {
            const int kb2 = (ks * 32 + kq * 8) * 2;
            bf16x8 ah[4], al[4], bh[4], bl[4];
            #pragma unroll
            for (int a2 = 0; a2 < 4; ++a2) {
                int ar = rowHalf + a2 * 16 + fm;
                ah[a2] = *(const bf16x8*)(Ah + ar * 144 + kb2);
                al[a2] = *(const bf16x8*)(Al + ar * 144 + kb2);
            }
            #pragma unroll
            for (int b2 = 0; b2 < 4; ++b2) {
                int br = colHalf + b2 * 16 + fm;
                bh[b2] = *(const bf16x8*)(Bh + br * 144 + kb2);
                bl[b2] = *(const bf16x8*)(Bl + br * 144 + kb2);
            }
            #pragma unroll
            for (int a2 = 0; a2 < 4; ++a2)
                #pragma unroll
                for (int b2 = 0; b2 < 4; ++b2) {
                    acc[a2][b2] = __builtin_amdgcn_mfma_f32_16x16x32_bf16(ah[a2], bh[b2], acc[a2][b2], 0, 0, 0);
                    acc[a2][b2] = __builtin_amdgcn_mfma_f32_16x16x32_bf16(ah[a2], bl[b2], acc[a2][b2], 0, 0, 0);
                    acc[a2][b2] = __builtin_amdgcn_mfma_f32_16x16x32_bf16(al[a2], bh[b2], acc[a2][b2], 0, 0, 0);
                }
        }
    }

    const bool selfm = (type != 0) && (ti == tj);
    float lsum = 0.f;
    #pragma unroll
    for (int a2 = 0; a2 < 4; ++a2) {
        int ib = rowHalf + a2 * 16 + kq * 4;
        #pragma unroll
        for (int b2 = 0; b2 < 4; ++b2) {
            int j = colHalf + b2 * 16 + fm;
            float qn = Qn[j];
            #pragma unroll
            for (int rg = 0; rg < 4; ++rg) {
                int i = ib + rg;
                float d2 = Pn[i] + qn - 2.0f * acc[a2][b2][rg];
                if (d2 > 0.f && !(selfm && i == j)) lsum += sqrtf(d2);
            }
        }
    }
    #pragma unroll
    for (int off = 32; off > 0; off >>= 1) lsum += __shfl_down(lsum, off, 64);
    if (lane == 0) wred[wv] = lsum;
    __syncthreads();
    if (tid == 0)
        partials[bid] = (wred[0] + wred[1] + wred[2] + wred[3]) * w;
}

__global__ __launch_bounds__(256)
void mmd_finalize_kernel(const float* __restrict__ partials, int n,
                         float* __restrict__ out, double scale) {
    __shared__ double sh[256];
    double s = 0.0;
    for (int i = threadIdx.x; i < n; i += 256) s += (double)partials[i];
    sh[threadIdx.x] = s;
    __syncthreads();
    for (int off = 128; off > 0; off >>= 1) {
        if ((int)threadIdx.x < off) sh[threadIdx.x] += sh[threadIdx.x + off];
        __syncthreads();
    }
    if (threadIdx.x == 0) out[0] = (float)(sh[0] * scale);
}

extern "C" void kernel_launch(void* const* d_in, const int* in_sizes, int n_in,
                              void* d_out, int out_size, void* d_ws, size_t ws_size,
                              hipStream_t stream) {
    const float* x = (const float*)d_in[0];
    const float* y = (const float*)d_in[1];
    float* out = (float*)d_out;

    const int n = in_sizes[0];
    const int B = n / (DSAMP * DIM);       // 128
    const double scale = 1.0 / ((double)B * (double)DSAMP * (double)DSAMP);

    float* partials = (float*)d_ws;
    if (B == 128 && ws_size >= (size_t)(128 * NPAIR) * 4) {
        const int nblocks = 128 * NPAIR;   // 2304 = 3.0 exact rounds @ 3 blk/CU
        mmd_fused<<<dim3(nblocks), dim3(256), 0, stream>>>(x, y, partials);
        mmd_finalize_kernel<<<dim3(1), dim3(256), 0, stream>>>(partials, nblocks, out, scale);
    } else {
        const int nblocks = B * 48;
        mmd_tile_fallback<<<dim3(nblocks), dim3(256), 0, stream>>>(x, y, partials);
        mmd_finalize_kernel<<<dim3(1), dim3(256), 0, stream>>>(partials, nblocks, out, scale);
    }
}

// Round 3
// 181.293 us; speedup vs baseline: 1.0083x; 1.0083x over previous
//
#include <hip/hip_runtime.h>

typedef __attribute__((ext_vector_type(8))) __bf16 bf16x8;
typedef __attribute__((ext_vector_type(4))) float f32x4;
typedef __attribute__((ext_vector_type(8))) unsigned short ushort8;

#define DSAMP 512
#define DIM   128
#define REG5  16384                // one staged region: 128 rows * 128 B (bf16, swizzled)
#define NPAIR 18                   // paired tiles per batch (2 tiles per block)

// ---------------------------------------------------------------------------
// Single-pass fused kernel, v2 (spill-free liveness). Each block owns one A
// row-panel of one batch, computes TWO 128x128 distance tiles against it.
// fp32 loaded directly from x/y, converted to bf16-hi (RNE) in registers,
// ds_written into the swizzled layout; exact fp32 row norms in-flight.
// Liveness discipline (the R2 lesson): acc[4][4] (64 AGPR) is the big
// resident; at most ONE 32-VGPR B-chunk lookahead is live at any time; the
// A panel is streamed in 8 independent 16-reg slices, never held whole.
// Fits the ~170-reg unified cap of __launch_bounds__(256,3) without scratch.
// ---------------------------------------------------------------------------
__constant__ unsigned char T_Asrc[NPAIR]  = {0,0,0,0,0,0,0,0, 1,1,1,1,1,1,1,1,1,1};
__constant__ unsigned char T_Ai[NPAIR]    = {0,0,1,1,1,2,2,3, 0,0,0,0,1,1,1,2,2,3};
__constant__ unsigned char T_Bsrc0[NPAIR] = {0,0,0,0,1,0,1,0, 1,1,0,0,1,1,0,1,0,1};
__constant__ unsigned char T_Bsrc1[NPAIR] = {0,0,0,1,1,0,1,1, 1,1,0,0,1,0,0,1,0,0};
__constant__ unsigned char T_Bj0[NPAIR]   = {0,2,1,3,2,2,2,3, 0,2,0,2,1,3,2,2,0,3};
__constant__ unsigned char T_Bj1[NPAIR]   = {1,3,2,1,3,3,3,3, 1,3,1,3,2,0,3,3,3,0};
// weight codes: 0 -> +1.0 (xy), 1 -> -1.0 (xx/yy off-diag), 2 -> -0.5 (diag)
__constant__ char          T_wc0[NPAIR]   = {2,1,2,1,0,2,0,2, 2,1,0,0,2,1,0,2,0,2};
__constant__ char          T_wc1[NPAIR]   = {1,1,1,0,0,1,0,0, 1,1,0,0,1,0,0,1,0,0};
__constant__ unsigned char T_d0[NPAIR]    = {1,0,1,0,0,1,0,1, 1,0,0,0,1,0,0,1,0,1};

__global__ __launch_bounds__(256, 3)
void mmd_fused(const float* __restrict__ x, const float* __restrict__ y,
               float* __restrict__ partials) {
    __shared__ __align__(16) char smem[3 * REG5];   // A c0 | A c1 | B (49152 B)
    __shared__ float Pn[128];
    __shared__ float Qn0[128];
    __shared__ float Qn1[128];
    __shared__ float wred[4];

    const int tid = threadIdx.x;
    const int bid = blockIdx.x;
    const int xcd = bid & 7;
    const int seq = bid >> 3;            // 0..287
    const int s   = seq % NPAIR;
    const int grp = seq / NPAIR;         // 0..15
    const int b   = xcd + 8 * grp;       // batch; all 18 pair-blocks adjacent

    const int Ai  = T_Ai[s];
    const int Bj0 = T_Bj0[s];
    const int Bj1 = T_Bj1[s];
    const float* Asrc  = T_Asrc[s]  ? y : x;
    const float* B0src = T_Bsrc0[s] ? y : x;
    const float* B1src = T_Bsrc1[s] ? y : x;
    const int wc0 = T_wc0[s], wc1 = T_wc1[s];
    const float w0 = (wc0 == 0) ? 1.0f : ((wc0 == 1) ? -1.0f : -0.5f);
    const float w1 = (wc1 == 0) ? 1.0f : ((wc1 == 1) ? -1.0f : -0.5f);
    const bool dg0 = T_d0[s] != 0;

    const size_t rowbase = (size_t)b * 512;
    const float* Ap  = Asrc  + (rowbase + (size_t)Ai  * 128) * 128;
    const float* Bp0 = B0src + (rowbase + (size_t)Bj0 * 128) * 128;
    const float* Bp1 = B1src + (rowbase + (size_t)Bj1 * 128) * 128;

    const int lane    = tid & 63;
    const int wv      = tid >> 6;
    const int rowHalf = (wv >> 1) * 64;
    const int colHalf = (wv & 1) * 64;
    const int fm      = lane & 15;
    const int kq      = lane >> 4;
    const int sw      = fm & 7;

    // convert 8 fp32 -> bf16-hi (RNE), write 16 B to LDS, return sum of squares
    auto cvt_write16 = [&](float4 v0, float4 v1, char* dst) -> float {
        float xs[8] = {v0.x, v0.y, v0.z, v0.w, v1.x, v1.y, v1.z, v1.w};
        ushort8 hv;
        float ss = 0.f;
        #pragma unroll
        for (int e = 0; e < 8; ++e) {
            ss += xs[e] * xs[e];
            unsigned ub = __float_as_uint(xs[e]);
            hv[e] = (unsigned short)((ub + 0x7fffu + ((ub >> 16) & 1u)) >> 16);
        }
        *(ushort8*)dst = hv;
        return ss;
    };

    // issue the 8 global loads for one B chunk (32 VGPRs, ONE live at a time)
    auto loadB = [&](const float* Bp, int cc, float4 (*vb)[2]) {
        #pragma unroll
        for (int it = 0; it < 4; ++it) {
            int u  = it * 256 + tid;          // (row 0..127, jb 0..7)
            int jb = u & 7;
            int r  = u >> 3;
            const float* g = Bp + (size_t)r * 128 + cc * 64 + jb * 8;
            vb[it][0] = ((const float4*)g)[0];
            vb[it][1] = ((const float4*)g)[1];
        }
    };
    // convert + write one B chunk to LDS, accumulate chunk norm partial
    auto writeB = [&](float4 (*vb)[2], float* Qn, bool add) {
        #pragma unroll
        for (int it = 0; it < 4; ++it) {
            int u  = it * 256 + tid;
            int jb = u & 7;
            int r  = u >> 3;
            float ss = cvt_write16(vb[it][0], vb[it][1],
                                   smem + 2 * REG5 + r * 128 + ((jb ^ (r & 7)) * 16));
            #pragma unroll
            for (int o = 4; o > 0; o >>= 1) ss += __shfl_down(ss, o, 8);
            if ((tid & 7) == 0) { if (add) Qn[r] += ss; else Qn[r] = ss; }
        }
    };

    f32x4 acc[4][4];
    auto zero_acc = [&]() {
        #pragma unroll
        for (int a2 = 0; a2 < 4; ++a2)
            #pragma unroll
            for (int b2 = 0; b2 < 4; ++b2)
                acc[a2][b2] = (f32x4){0.f, 0.f, 0.f, 0.f};
    };

    auto compute = [&](int creg) {
        const char* Ab = smem + creg * REG5;
        const char* Bb = smem + 2 * REG5;
        #pragma unroll
        for (int ks = 0; ks < 2; ++ks) {
            const int jx = ((ks * 4 + kq) ^ sw) * 16;
            bf16x8 ah[4], bh[4];
            #pragma unroll
            for (int a2 = 0; a2 < 4; ++a2)
                ah[a2] = *(const bf16x8*)(Ab + (rowHalf + a2 * 16 + fm) * 128 + jx);
            #pragma unroll
            for (int b2 = 0; b2 < 4; ++b2)
                bh[b2] = *(const bf16x8*)(Bb + (colHalf + b2 * 16 + fm) * 128 + jx);
            __builtin_amdgcn_s_setprio(1);
            #pragma unroll
            for (int a2 = 0; a2 < 4; ++a2)
                #pragma unroll
                for (int b2 = 0; b2 < 4; ++b2)
                    acc[a2][b2] = __builtin_amdgcn_mfma_f32_16x16x32_bf16(
                        ah[a2], bh[b2], acc[a2][b2], 0, 0, 0);
            __builtin_amdgcn_s_setprio(0);
        }
    };

    auto tile_sum = [&](const float* Qn, bool dg) -> float {
        float Pr[16], Qc[4];
        #pragma unroll
        for (int a2 = 0; a2 < 4; ++a2)
            #pragma unroll
            for (int rg2 = 0; rg2 < 4; ++rg2)
                Pr[a2 * 4 + rg2] = Pn[rowHalf + a2 * 16 + kq * 4 + rg2];
        #pragma unroll
        for (int b2 = 0; b2 < 4; ++b2) Qc[b2] = Qn[colHalf + b2 * 16 + fm];
        float ls = 0.f;
        if (dg) {
            #pragma unroll
            for (int a2 = 0; a2 < 4; ++a2)
                #pragma unroll
                for (int b2 = 0; b2 < 4; ++b2)
                    #pragma unroll
                    for (int rg2 = 0; rg2 < 4; ++rg2) {
                        float d2 = fmaf(-2.0f, acc[a2][b2][rg2], Pr[a2 * 4 + rg2] + Qc[b2]);
                        float v  = __builtin_amdgcn_sqrtf(fmaxf(d2, 0.0f));
                        if ((rowHalf + a2 * 16 + kq * 4 + rg2) == (colHalf + b2 * 16 + fm)) v = 0.f;
                        ls += v;
                    }
        } else {
            #pragma unroll
            for (int a2 = 0; a2 < 4; ++a2)
                #pragma unroll
                for (int b2 = 0; b2 < 4; ++b2)
                    #pragma unroll
                    for (int rg2 = 0; rg2 < 4; ++rg2) {
                        float d2 = fmaf(-2.0f, acc[a2][b2][rg2], Pr[a2 * 4 + rg2] + Qc[b2]);
                        ls += __builtin_amdgcn_sqrtf(fmaxf(d2, 0.0f));
                    }
        }
        return ls;
    };

    // ---- phase S: B0c0 issue-early (32 regs), A streamed in 16-reg slices ----
    float4 vb0[4][2];
    loadB(Bp0, 0, vb0);                    // latency hidden under A streaming
    #pragma unroll
    for (int it = 0; it < 8; ++it) {
        int u  = it * 256 + tid;           // (row, c, jb)
        int jb = u & 7;
        int cc = (u >> 3) & 1;
        int r  = u >> 4;
        const float* g = Ap + (size_t)r * 128 + cc * 64 + jb * 8;
        float4 v0 = ((const float4*)g)[0];
        float4 v1 = ((const float4*)g)[1];
        float ss = cvt_write16(v0, v1,
                               smem + cc * REG5 + r * 128 + ((jb ^ (r & 7)) * 16));
        // full-row norm: 16 lanes = (c0 jb0..7, c1 jb0..7)
        #pragma unroll
        for (int o = 8; o > 0; o >>= 1) ss += __shfl_down(ss, o, 16);
        if ((tid & 15) == 0) Pn[r] = ss;
    }
    writeB(vb0, Qn0, false);               // vb0 dies here
    __syncthreads();                       // A + B(t0,c0) staged

    // ---- tile 0 ----
    zero_acc();
    float4 vb1[4][2];
    loadB(Bp0, 1, vb1);                    // issue-early: latency under compute
    compute(0);
    __syncthreads();                       // B buf free
    writeB(vb1, Qn0, true);                // Qn0 complete; vb1 dies
    __syncthreads();                       // B(t0,c1) staged
    float4 vb2[4][2];
    loadB(Bp1, 0, vb2);
    compute(1);
    float lsum = w0 * tile_sum(Qn0, dg0);
    zero_acc();
    __syncthreads();                       // B buf free
    writeB(vb2, Qn1, false);               // vb2 dies
    __syncthreads();                       // B(t1,c0) staged

    // ---- tile 1 ----
    float4 vb3[4][2];
    loadB(Bp1, 1, vb3);
    compute(0);
    __syncthreads();                       // B buf free
    writeB(vb3, Qn1, true);                // Qn1 complete; vb3 dies
    __syncthreads();                       // B(t1,c1) staged
    compute(1);
    lsum += w1 * tile_sum(Qn1, false);

    #pragma unroll
    for (int off = 32; off > 0; off >>= 1) lsum += __shfl_down(lsum, off, 64);
    if (lane == 0) wred[wv] = lsum;
    __syncthreads();
    if (tid == 0)
        partials[bid] = wred[0] + wred[1] + wred[2] + wred[3];
}

// ---------------------------------------------------------------------------
// Fallback (in-kernel 3-term conversion, full 48 tiles/batch) if B != 128.
// ---------------------------------------------------------------------------
__global__ __launch_bounds__(256, 2)
void mmd_tile_fallback(const float* __restrict__ x, const float* __restrict__ y,
                       float* __restrict__ partials) {
    __shared__ __align__(16) char smem[4 * 128 * 144];
    __shared__ float Pn[128];
    __shared__ float Qn[128];
    __shared__ float wred[4];

    char* Ah = smem;
    char* Al = smem + 1 * 128 * 144;
    char* Bh = smem + 2 * 128 * 144;
    char* Bl = smem + 3 * 128 * 144;

    const int tid  = threadIdx.x;
    const int bid  = blockIdx.x;
    const int tj   = bid & 3;
    const int ti   = (bid >> 2) & 3;
    const int type = (bid >> 4) % 3;
    const int b    = bid / 48;

    const float* Xb = x + (size_t)b * DSAMP * DIM;
    const float* Yb = y + (size_t)b * DSAMP * DIM;
    const float* Pp; const float* Qp; float w;
    if (type == 0)      { Pp = Xb; Qp = Yb; w = 1.0f;  }
    else if (type == 1) { Pp = Xb; Qp = Xb; w = -0.5f; }
    else                { Pp = Yb; Qp = Yb; w = -0.5f; }
    Pp += (size_t)ti * 128 * DIM;
    Qp += (size_t)tj * 128 * DIM;

    {
        const float* rp = (tid < 128) ? (Pp + (size_t)tid * DIM)
                                      : (Qp + (size_t)(tid - 128) * DIM);
        float s = 0.f;
        #pragma unroll
        for (int k4 = 0; k4 < 32; ++k4) {
            float4 v = ((const float4*)rp)[k4];
            s += v.x * v.x + v.y * v.y + v.z * v.z + v.w * v.w;
        }
        if (tid < 128) Pn[tid] = s; else Qn[tid - 128] = s;
    }

    const int lane    = tid & 63;
    const int wv      = tid >> 6;
    const int rowHalf = (wv >> 1) * 64;
    const int colHalf = (wv & 1) * 64;
    const int fm      = lane & 15;
    const int kq      = lane >> 4;

    f32x4 acc[4][4];
    #pragma unroll
    for (int a2 = 0; a2 < 4; ++a2)
        #pragma unroll
        for (int b2 = 0; b2 < 4; ++b2)
            acc[a2][b2] = (f32x4){0.f, 0.f, 0.f, 0.f};

    for (int c = 0; c < 2; ++c) {
        if (c) __syncthreads();
        #pragma unroll
        for (int side = 0; side < 2; ++side) {
            const float* sp = side ? Qp : Pp;
            char* dh = side ? Bh : Ah;
            char* dl = side ? Bl : Al;
            #pragma unroll
            for (int it = 0; it < 4; ++it) {
                int u  = it * 256 + tid;
                int r  = u >> 3;
                int c8 = u & 7;
                const float* g = sp + (size_t)r * DIM + c * 64 + c8 * 8;
                float4 v0 = ((const float4*)g)[0];
                float4 v1 = ((const float4*)g)[1];
                float xs[8] = {v0.x, v0.y, v0.z, v0.w, v1.x, v1.y, v1.z, v1.w};
                ushort8 hv, lv;
                #pragma unroll
                for (int e = 0; e < 8; ++e) {
                    float xv = xs[e];
                    unsigned ub = __float_as_uint(xv);
                    unsigned hr = (ub + 0x7fffu + ((ub >> 16) & 1u)) >> 16;
                    float hf = __uint_as_float(hr << 16);
                    float rs = xv - hf;
                    unsigned ul = __float_as_uint(rs);
                    unsigned lr = (ul + 0x7fffu + ((ul >> 16) & 1u)) >> 16;
                    hv[e] = (unsigned short)hr;
                    lv[e] = (unsigned short)lr;
                }
                *(ushort8*)(dh + r * 144 + c8 * 16) = hv;
                *(ushort8*)(dl + r * 144 + c8 * 16) = lv;
            }
        }
        __syncthreads();
        #pragma unroll
        for (int ks = 0; ks < 2; ++ks) {
            const int kb2 = (ks * 32 + kq * 8) * 2;
            bf16x8 ah[4], al[4], bh[4], bl[4];
            #pragma unroll
            for (int a2 = 0; a2 < 4; ++a2) {
                int ar = rowHalf + a2 * 16 + fm;
                ah[a2] = *(const bf16x8*)(Ah + ar * 144 + kb2);
                al[a2] = *(const bf16x8*)(Al + ar * 144 + kb2);
            }
            #pragma unroll
            for (int b2 = 0; b2 < 4; ++b2) {
                int br = colHalf + b2 * 16 + fm;
                bh[b2] = *(const bf16x8*)(Bh + br * 144 + kb2);
                bl[b2] = *(const bf16x8*)(Bl + br * 144 + kb2);
            }
            #pragma unroll
            for (int a2 = 0; a2 < 4; ++a2)
                #pragma unroll
                for (int b2 = 0; b2 < 4; ++b2) {
                    acc[a2][b2] = __builtin_amdgcn_mfma_f32_16x16x32_bf16(ah[a2], bh[b2], acc[a2][b2], 0, 0, 0);
                    acc[a2][b2] = __builtin_amdgcn_mfma_f32_16x16x32_bf16(ah[a2], bl[b2], acc[a2][b2], 0, 0, 0);
                    acc[a2][b2] = __builtin_amdgcn_mfma_f32_16x16x32_bf16(al[a2], bh[b2], acc[a2][b2], 0, 0, 0);
                }
        }
    }

    const bool selfm = (type != 0) && (ti == tj);
    float lsum = 0.f;
    #pragma unroll
    for (int a2 = 0; a2 < 4; ++a2) {
        int ib = rowHalf + a2 * 16 + kq * 4;
        #pragma unroll
        for (int b2 = 0; b2 < 4; ++b2) {
            int j = colHalf + b2 * 16 + fm;
            float qn = Qn[j];
            #pragma unroll
            for (int rg = 0; rg < 4; ++rg) {
                int i = ib + rg;
                float d2 = Pn[i] + qn - 2.0f * acc[a2][b2][rg];
                if (d2 > 0.f && !(selfm && i == j)) lsum += sqrtf(d2);
            }
        }
    }
    #pragma unroll
    for (int off = 32; off > 0; off >>= 1) lsum += __shfl_down(lsum, off, 64);
    if (lane == 0) wred[wv] = lsum;
    __syncthreads();
    if (tid == 0)
        partials[bid] = (wred[0] + wred[1] + wred[2] + wred[3]) * w;
}

__global__ __launch_bounds__(256)
void mmd_finalize_kernel(const float* __restrict__ partials, int n,
                         float* __restrict__ out, double scale) {
    __shared__ double sh[256];
    double s = 0.0;
    for (int i = threadIdx.x; i < n; i += 256) s += (double)partials[i];
    sh[threadIdx.x] = s;
    __syncthreads();
    for (int off = 128; off > 0; off >>= 1) {
        if ((int)threadIdx.x < off) sh[threadIdx.x] += sh[threadIdx.x + off];
        __syncthreads();
    }
    if (threadIdx.x == 0) out[0] = (float)(sh[0] * scale);
}

extern "C" void kernel_launch(void* const* d_in, const int* in_sizes, int n_in,
                              void* d_out, int out_size, void* d_ws, size_t ws_size,
                              hipStream_t stream) {
    const float* x = (const float*)d_in[0];
    const float* y = (const float*)d_in[1];
    float* out = (float*)d_out;

    const int n = in_sizes[0];
    const int B = n / (DSAMP * DIM);       // 128
    const double scale = 1.0 / ((double)B * (double)DSAMP * (double)DSAMP);

    float* partials = (float*)d_ws;
    if (B == 128 && ws_size >= (size_t)(128 * NPAIR) * 4) {
        const int nblocks = 128 * NPAIR;   // 2304 = 3.0 exact rounds @ 3 blk/CU
        mmd_fused<<<dim3(nblocks), dim3(256), 0, stream>>>(x, y, partials);
        mmd_finalize_kernel<<<dim3(1), dim3(256), 0, stream>>>(partials, nblocks, out, scale);
    } else {
        const int nblocks = B * 48;
        mmd_tile_fallback<<<dim3(nblocks), dim3(256), 0, stream>>>(x, y, partials);
        mmd_finalize_kernel<<<dim3(1), dim3(256), 0, stream>>>(partials, nblocks, out, scale);
    }
}

// Round 4
// 159.026 us; speedup vs baseline: 1.1495x; 1.1400x over previous
//
#include <hip/hip_runtime.h>

typedef __attribute__((ext_vector_type(8))) __bf16 bf16x8;
typedef __attribute__((ext_vector_type(4))) float f32x4;
typedef __attribute__((ext_vector_type(8))) unsigned short ushort8;

#define DSAMP 512
#define DIM   128
#define REG5  16384                // one staged region: 128 rows * 128 B (bf16, swizzled)
#define NPAIR 18                   // paired tiles per batch (2 tiles per block)

// ---------------------------------------------------------------------------
// Single-pass fused kernel, v3. R2/R3 lesson: array locals passed through
// lambda pointers (float4 (*)[2], float xs[8]) never get SROA'd -> scratch
// (87 MB of stack traffic, VGPR_Count stuck at 84). v3 uses NAMED float4
// registers p0..p7 for the one in-flight B chunk and an arrayless convert,
// so every staged value is an SSA scalar the compiler must keep in VGPRs.
// Schedule, swizzle, pair table identical to R2.
// ---------------------------------------------------------------------------
__constant__ unsigned char T_Asrc[NPAIR]  = {0,0,0,0,0,0,0,0, 1,1,1,1,1,1,1,1,1,1};
__constant__ unsigned char T_Ai[NPAIR]    = {0,0,1,1,1,2,2,3, 0,0,0,0,1,1,1,2,2,3};
__constant__ unsigned char T_Bsrc0[NPAIR] = {0,0,0,0,1,0,1,0, 1,1,0,0,1,1,0,1,0,1};
__constant__ unsigned char T_Bsrc1[NPAIR] = {0,0,0,1,1,0,1,1, 1,1,0,0,1,0,0,1,0,0};
__constant__ unsigned char T_Bj0[NPAIR]   = {0,2,1,3,2,2,2,3, 0,2,0,2,1,3,2,2,0,3};
__constant__ unsigned char T_Bj1[NPAIR]   = {1,3,2,1,3,3,3,3, 1,3,1,3,2,0,3,3,3,0};
// weight codes: 0 -> +1.0 (xy), 1 -> -1.0 (xx/yy off-diag), 2 -> -0.5 (diag)
__constant__ char          T_wc0[NPAIR]   = {2,1,2,1,0,2,0,2, 2,1,0,0,2,1,0,2,0,2};
__constant__ char          T_wc1[NPAIR]   = {1,1,1,0,0,1,0,0, 1,1,0,0,1,0,0,1,0,0};
__constant__ unsigned char T_d0[NPAIR]    = {1,0,1,0,0,1,0,1, 1,0,0,0,1,0,0,1,0,1};

// arrayless fp32x8 -> bf16x8 RNE convert + sum of squares (all SSA values)
__device__ __forceinline__ ushort8 cvt8(float4 v0, float4 v1, float& ss) {
    ss = v0.x * v0.x + v0.y * v0.y + v0.z * v0.z + v0.w * v0.w
       + v1.x * v1.x + v1.y * v1.y + v1.z * v1.z + v1.w * v1.w;
    ushort8 hv;
    unsigned u;
    u = __float_as_uint(v0.x); hv[0] = (unsigned short)((u + 0x7fffu + ((u >> 16) & 1u)) >> 16);
    u = __float_as_uint(v0.y); hv[1] = (unsigned short)((u + 0x7fffu + ((u >> 16) & 1u)) >> 16);
    u = __float_as_uint(v0.z); hv[2] = (unsigned short)((u + 0x7fffu + ((u >> 16) & 1u)) >> 16);
    u = __float_as_uint(v0.w); hv[3] = (unsigned short)((u + 0x7fffu + ((u >> 16) & 1u)) >> 16);
    u = __float_as_uint(v1.x); hv[4] = (unsigned short)((u + 0x7fffu + ((u >> 16) & 1u)) >> 16);
    u = __float_as_uint(v1.y); hv[5] = (unsigned short)((u + 0x7fffu + ((u >> 16) & 1u)) >> 16);
    u = __float_as_uint(v1.z); hv[6] = (unsigned short)((u + 0x7fffu + ((u >> 16) & 1u)) >> 16);
    u = __float_as_uint(v1.w); hv[7] = (unsigned short)((u + 0x7fffu + ((u >> 16) & 1u)) >> 16);
    return hv;
}

// issue 8 global loads for one B chunk into NAMED registers p0..p7
#define LOADB(Bp, cc) do {                                                    \
    const float* gb_ = (Bp) + (size_t)rB * 128 + (cc) * 64 + jbB * 8;         \
    p0 = ((const float4*)gb_)[0];          p1 = ((const float4*)gb_)[1];      \
    p2 = ((const float4*)(gb_ + 4096))[0]; p3 = ((const float4*)(gb_ + 4096))[1]; \
    p4 = ((const float4*)(gb_ + 8192))[0]; p5 = ((const float4*)(gb_ + 8192))[1]; \
    p6 = ((const float4*)(gb_ +12288))[0]; p7 = ((const float4*)(gb_ +12288))[1]; \
} while (0)

#define RED8(sv) do {                       \
    sv += __shfl_down(sv, 4, 8);            \
    sv += __shfl_down(sv, 2, 8);            \
    sv += __shfl_down(sv, 1, 8);            \
} while (0)

// convert + ds_write the staged chunk, accumulate per-row norm partials
#define WRITEB(QnArr, add) do {                                               \
    float ssw_; ushort8 hw_;                                                  \
    hw_ = cvt8(p0, p1, ssw_); *(ushort8*)(dstB +     0) = hw_; RED8(ssw_);    \
    if ((tid & 7) == 0) { if (add) (QnArr)[rB]      += ssw_; else (QnArr)[rB]      = ssw_; } \
    hw_ = cvt8(p2, p3, ssw_); *(ushort8*)(dstB +  4096) = hw_; RED8(ssw_);    \
    if ((tid & 7) == 0) { if (add) (QnArr)[rB + 32] += ssw_; else (QnArr)[rB + 32] = ssw_; } \
    hw_ = cvt8(p4, p5, ssw_); *(ushort8*)(dstB +  8192) = hw_; RED8(ssw_);    \
    if ((tid & 7) == 0) { if (add) (QnArr)[rB + 64] += ssw_; else (QnArr)[rB + 64] = ssw_; } \
    hw_ = cvt8(p6, p7, ssw_); *(ushort8*)(dstB + 12288) = hw_; RED8(ssw_);    \
    if ((tid & 7) == 0) { if (add) (QnArr)[rB + 96] += ssw_; else (QnArr)[rB + 96] = ssw_; } \
} while (0)

__global__ __launch_bounds__(256, 3)
void mmd_fused(const float* __restrict__ x, const float* __restrict__ y,
               float* __restrict__ partials) {
    __shared__ __align__(16) char smem[3 * REG5];   // A c0 | A c1 | B (49152 B)
    __shared__ float Pn[128];
    __shared__ float Qn0[128];
    __shared__ float Qn1[128];
    __shared__ float wred[4];

    const int tid = threadIdx.x;
    const int bid = blockIdx.x;
    const int xcd = bid & 7;
    const int seq = bid >> 3;            // 0..287
    const int s   = seq % NPAIR;
    const int grp = seq / NPAIR;         // 0..15
    const int b   = xcd + 8 * grp;       // batch; all 18 pair-blocks adjacent

    const int Ai  = T_Ai[s];
    const int Bj0 = T_Bj0[s];
    const int Bj1 = T_Bj1[s];
    const float* Asrc  = T_Asrc[s]  ? y : x;
    const float* B0src = T_Bsrc0[s] ? y : x;
    const float* B1src = T_Bsrc1[s] ? y : x;
    const int wc0 = T_wc0[s], wc1 = T_wc1[s];
    const float w0 = (wc0 == 0) ? 1.0f : ((wc0 == 1) ? -1.0f : -0.5f);
    const float w1 = (wc1 == 0) ? 1.0f : ((wc1 == 1) ? -1.0f : -0.5f);
    const bool dg0 = T_d0[s] != 0;

    const size_t rowbase = (size_t)b * 512;
    const float* Ap  = Asrc  + (rowbase + (size_t)Ai  * 128) * 128;
    const float* Bp0 = B0src + (rowbase + (size_t)Bj0 * 128) * 128;
    const float* Bp1 = B1src + (rowbase + (size_t)Bj1 * 128) * 128;

    const int lane    = tid & 63;
    const int wv      = tid >> 6;
    const int rowHalf = (wv >> 1) * 64;
    const int colHalf = (wv & 1) * 64;
    const int fm      = lane & 15;
    const int kq      = lane >> 4;
    const int sw      = fm & 7;

    // B staging thread map: 8 lanes per row, 32 row-quads
    const int jbB = tid & 7;
    const int rB  = tid >> 3;            // 0..31
    char* dstB = smem + 2 * REG5 + rB * 128 + ((jbB ^ (rB & 7)) * 16);

    float4 p0, p1, p2, p3, p4, p5, p6, p7;   // the ONE in-flight B chunk

    f32x4 acc[4][4];
    auto zero_acc = [&]() {
        #pragma unroll
        for (int a2 = 0; a2 < 4; ++a2)
            #pragma unroll
            for (int b2 = 0; b2 < 4; ++b2)
                acc[a2][b2] = (f32x4){0.f, 0.f, 0.f, 0.f};
    };

    auto compute = [&](int creg) {
        const char* Ab = smem + creg * REG5;
        const char* Bb = smem + 2 * REG5;
        #pragma unroll
        for (int ks = 0; ks < 2; ++ks) {
            const int jx = ((ks * 4 + kq) ^ sw) * 16;
            bf16x8 ah[4], bh[4];
            #pragma unroll
            for (int a2 = 0; a2 < 4; ++a2)
                ah[a2] = *(const bf16x8*)(Ab + (rowHalf + a2 * 16 + fm) * 128 + jx);
            #pragma unroll
            for (int b2 = 0; b2 < 4; ++b2)
                bh[b2] = *(const bf16x8*)(Bb + (colHalf + b2 * 16 + fm) * 128 + jx);
            __builtin_amdgcn_s_setprio(1);
            #pragma unroll
            for (int a2 = 0; a2 < 4; ++a2)
                #pragma unroll
                for (int b2 = 0; b2 < 4; ++b2)
                    acc[a2][b2] = __builtin_amdgcn_mfma_f32_16x16x32_bf16(
                        ah[a2], bh[b2], acc[a2][b2], 0, 0, 0);
            __builtin_amdgcn_s_setprio(0);
        }
    };

    auto tile_sum = [&](const float* Qn, bool dg) -> float {
        float Pr[16], Qc[4];
        #pragma unroll
        for (int a2 = 0; a2 < 4; ++a2)
            #pragma unroll
            for (int rg2 = 0; rg2 < 4; ++rg2)
                Pr[a2 * 4 + rg2] = Pn[rowHalf + a2 * 16 + kq * 4 + rg2];
        #pragma unroll
        for (int b2 = 0; b2 < 4; ++b2) Qc[b2] = Qn[colHalf + b2 * 16 + fm];
        float ls = 0.f;
        if (dg) {
            #pragma unroll
            for (int a2 = 0; a2 < 4; ++a2)
                #pragma unroll
                for (int b2 = 0; b2 < 4; ++b2)
                    #pragma unroll
                    for (int rg2 = 0; rg2 < 4; ++rg2) {
                        float d2 = fmaf(-2.0f, acc[a2][b2][rg2], Pr[a2 * 4 + rg2] + Qc[b2]);
                        float v  = __builtin_amdgcn_sqrtf(fmaxf(d2, 0.0f));
                        if ((rowHalf + a2 * 16 + kq * 4 + rg2) == (colHalf + b2 * 16 + fm)) v = 0.f;
                        ls += v;
                    }
        } else {
            #pragma unroll
            for (int a2 = 0; a2 < 4; ++a2)
                #pragma unroll
                for (int b2 = 0; b2 < 4; ++b2)
                    #pragma unroll
                    for (int rg2 = 0; rg2 < 4; ++rg2) {
                        float d2 = fmaf(-2.0f, acc[a2][b2][rg2], Pr[a2 * 4 + rg2] + Qc[b2]);
                        ls += __builtin_amdgcn_sqrtf(fmaxf(d2, 0.0f));
                    }
        }
        return ls;
    };

    // ---- phase S: B0c0 issue-early into p0..p7, A streamed slice-by-slice ----
    LOADB(Bp0, 0);                         // latency hidden under A streaming
    #pragma unroll
    for (int it = 0; it < 8; ++it) {
        int u  = it * 256 + tid;           // (row, c, jb)
        int jb = u & 7;
        int cc = (u >> 3) & 1;
        int r  = u >> 4;
        const float* g = Ap + (size_t)r * 128 + cc * 64 + jb * 8;
        float4 v0 = ((const float4*)g)[0];
        float4 v1 = ((const float4*)g)[1];
        float ss;
        ushort8 hv = cvt8(v0, v1, ss);
        *(ushort8*)(smem + cc * REG5 + r * 128 + ((jb ^ (r & 7)) * 16)) = hv;
        // full-row norm: 16 lanes = (c0 jb0..7, c1 jb0..7)
        ss += __shfl_down(ss, 8, 16);
        ss += __shfl_down(ss, 4, 16);
        ss += __shfl_down(ss, 2, 16);
        ss += __shfl_down(ss, 1, 16);
        if ((tid & 15) == 0) Pn[r] = ss;
    }
    WRITEB(Qn0, false);                    // p0..p7 die here
    __syncthreads();                       // A + B(t0,c0) staged

    // ---- tile 0 ----
    zero_acc();
    LOADB(Bp0, 1);                         // issue-early: latency under compute
    compute(0);
    __syncthreads();                       // B buf free
    WRITEB(Qn0, true);                     // Qn0 complete
    __syncthreads();                       // B(t0,c1) staged
    LOADB(Bp1, 0);
    compute(1);
    float lsum = w0 * tile_sum(Qn0, dg0);
    zero_acc();
    __syncthreads();                       // B buf free
    WRITEB(Qn1, false);
    __syncthreads();                       // B(t1,c0) staged

    // ---- tile 1 ----
    LOADB(Bp1, 1);
    compute(0);
    __syncthreads();                       // B buf free
    WRITEB(Qn1, true);                     // Qn1 complete
    __syncthreads();                       // B(t1,c1) staged
    compute(1);
    lsum += w1 * tile_sum(Qn1, false);

    #pragma unroll
    for (int off = 32; off > 0; off >>= 1) lsum += __shfl_down(lsum, off, 64);
    if (lane == 0) wred[wv] = lsum;
    __syncthreads();
    if (tid == 0)
        partials[bid] = wred[0] + wred[1] + wred[2] + wred[3];
}

// ---------------------------------------------------------------------------
// Fallback (in-kernel 3-term conversion, full 48 tiles/batch) if B != 128.
// ---------------------------------------------------------------------------
__global__ __launch_bounds__(256, 2)
void mmd_tile_fallback(const float* __restrict__ x, const float* __restrict__ y,
                       float* __restrict__ partials) {
    __shared__ __align__(16) char smem[4 * 128 * 144];
    __shared__ float Pn[128];
    __shared__ float Qn[128];
    __shared__ float wred[4];

    char* Ah = smem;
    char* Al = smem + 1 * 128 * 144;
    char* Bh = smem + 2 * 128 * 144;
    char* Bl = smem + 3 * 128 * 144;

    const int tid  = threadIdx.x;
    const int bid  = blockIdx.x;
    const int tj   = bid & 3;
    const int ti   = (bid >> 2) & 3;
    const int type = (bid >> 4) % 3;
    const int b    = bid / 48;

    const float* Xb = x + (size_t)b * DSAMP * DIM;
    const float* Yb = y + (size_t)b * DSAMP * DIM;
    const float* Pp; const float* Qp; float w;
    if (type == 0)      { Pp = Xb; Qp = Yb; w = 1.0f;  }
    else if (type == 1) { Pp = Xb; Qp = Xb; w = -0.5f; }
    else                { Pp = Yb; Qp = Yb; w = -0.5f; }
    Pp += (size_t)ti * 128 * DIM;
    Qp += (size_t)tj * 128 * DIM;

    {
        const float* rp = (tid < 128) ? (Pp + (size_t)tid * DIM)
                                      : (Qp + (size_t)(tid - 128) * DIM);
        float s = 0.f;
        #pragma unroll
        for (int k4 = 0; k4 < 32; ++k4) {
            float4 v = ((const float4*)rp)[k4];
            s += v.x * v.x + v.y * v.y + v.z * v.z + v.w * v.w;
        }
        if (tid < 128) Pn[tid] = s; else Qn[tid - 128] = s;
    }

    const int lane    = tid & 63;
    const int wv      = tid >> 6;
    const int rowHalf = (wv >> 1) * 64;
    const int colHalf = (wv & 1) * 64;
    const int fm      = lane & 15;
    const int kq      = lane >> 4;

    f32x4 acc[4][4];
    #pragma unroll
    for (int a2 = 0; a2 < 4; ++a2)
        #pragma unroll
        for (int b2 = 0; b2 < 4; ++b2)
            acc[a2][b2] = (f32x4){0.f, 0.f, 0.f, 0.f};

    for (int c = 0; c < 2; ++c) {
        if (c) __syncthreads();
        #pragma unroll
        for (int side = 0; side < 2; ++side) {
            const float* sp = side ? Qp : Pp;
            char* dh = side ? Bh : Ah;
            char* dl = side ? Bl : Al;
            #pragma unroll
            for (int it = 0; it < 4; ++it) {
                int u  = it * 256 + tid;
                int r  = u >> 3;
                int c8 = u & 7;
                const float* g = sp + (size_t)r * DIM + c * 64 + c8 * 8;
                float4 v0 = ((const float4*)g)[0];
                float4 v1 = ((const float4*)g)[1];
                float xs[8] = {v0.x, v0.y, v0.z, v0.w, v1.x, v1.y, v1.z, v1.w};
                ushort8 hv, lv;
                #pragma unroll
                for (int e = 0; e < 8; ++e) {
                    float xv = xs[e];
                    unsigned ub = __float_as_uint(xv);
                    unsigned hr = (ub + 0x7fffu + ((ub >> 16) & 1u)) >> 16;
                    float hf = __uint_as_float(hr << 16);
                    float rs = xv - hf;
                    unsigned ul = __float_as_uint(rs);
                    unsigned lr = (ul + 0x7fffu + ((ul >> 16) & 1u)) >> 16;
                    hv[e] = (unsigned short)hr;
                    lv[e] = (unsigned short)lr;
                }
                *(ushort8*)(dh + r * 144 + c8 * 16) = hv;
                *(ushort8*)(dl + r * 144 + c8 * 16) = lv;
            }
        }
        __syncthreads();
        #pragma unroll
        for (int ks = 0; ks < 2; ++ks) {
            const int kb2 = (ks * 32 + kq * 8) * 2;
            bf16x8 ah[4], al[4], bh[4], bl[4];
            #pragma unroll
            for (int a2 = 0; a2 < 4; ++a2) {
                int ar = rowHalf + a2 * 16 + fm;
                ah[a2] = *(const bf16x8*)(Ah + ar * 144 + kb2);
                al[a2] = *(const bf16x8*)(Al + ar * 144 + kb2);
            }
            #pragma unroll
            for (int b2 = 0; b2 < 4; ++b2) {
                int br = colHalf + b2 * 16 + fm;
                bh[b2] = *(const bf16x8*)(Bh + br * 144 + kb2);
                bl[b2] = *(const bf16x8*)(Bl + br * 144 + kb2);
            }
            #pragma unroll
            for (int a2 = 0; a2 < 4; ++a2)
                #pragma unroll
                for (int b2 = 0; b2 < 4; ++b2) {
                    acc[a2][b2] = __builtin_amdgcn_mfma_f32_16x16x32_bf16(ah[a2], bh[b2], acc[a2][b2], 0, 0, 0);
                    acc[a2][b2] = __builtin_amdgcn_mfma_f32_16x16x32_bf16(ah[a2], bl[b2], acc[a2][b2], 0, 0, 0);
                    acc[a2][b2] = __builtin_amdgcn_mfma_f32_16x16x32_bf16(al[a2], bh[b2], acc[a2][b2], 0, 0, 0);
                }
        }
    }

    const bool selfm = (type != 0) && (ti == tj);
    float lsum = 0.f;
    #pragma unroll
    for (int a2 = 0; a2 < 4; ++a2) {
        int ib = rowHalf + a2 * 16 + kq * 4;
        #pragma unroll
        for (int b2 = 0; b2 < 4; ++b2) {
            int j = colHalf + b2 * 16 + fm;
            float qn = Qn[j];
            #pragma unroll
            for (int rg = 0; rg < 4; ++rg) {
                int i = ib + rg;
                float d2 = Pn[i] + qn - 2.0f * acc[a2][b2][rg];
                if (d2 > 0.f && !(selfm && i == j)) lsum += sqrtf(d2);
            }
        }
    }
    #pragma unroll
    for (int off = 32; off > 0; off >>= 1) lsum += __shfl_down(lsum, off, 64);
    if (lane == 0) wred[wv] = lsum;
    __syncthreads();
    if (tid == 0)
        partials[bid] = (wred[0] + wred[1] + wred[2] + wred[3]) * w;
}

__global__ __launch_bounds__(256)
void mmd_finalize_kernel(const float* __restrict__ partials, int n,
                         float* __restrict__ out, double scale) {
    __shared__ double sh[256];
    double s = 0.0;
    for (int i = threadIdx.x; i < n; i += 256) s += (double)partials[i];
    sh[threadIdx.x] = s;
    __syncthreads();
    for (int off = 128; off > 0; off >>= 1) {
        if ((int)threadIdx.x < off) sh[threadIdx.x] += sh[threadIdx.x + off];
        __syncthreads();
    }
    if (threadIdx.x == 0) out[0] = (float)(sh[0] * scale);
}

extern "C" void kernel_launch(void* const* d_in, const int* in_sizes, int n_in,
                              void* d_out, int out_size, void* d_ws, size_t ws_size,
                              hipStream_t stream) {
    const float* x = (const float*)d_in[0];
    const float* y = (const float*)d_in[1];
    float* out = (float*)d_out;

    const int n = in_sizes[0];
    const int B = n / (DSAMP * DIM);       // 128
    const double scale = 1.0 / ((double)B * (double)DSAMP * (double)DSAMP);

    float* partials = (float*)d_ws;
    if (B == 128 && ws_size >= (size_t)(128 * NPAIR) * 4) {
        const int nblocks = 128 * NPAIR;   // 2304 = 3.0 exact rounds @ 3 blk/CU
        mmd_fused<<<dim3(nblocks), dim3(256), 0, stream>>>(x, y, partials);
        mmd_finalize_kernel<<<dim3(1), dim3(256), 0, stream>>>(partials, nblocks, out, scale);
    } else {
        const int nblocks = B * 48;
        mmd_tile_fallback<<<dim3(nblocks), dim3(256), 0, stream>>>(x, y, partials);
        mmd_finalize_kernel<<<dim3(1), dim3(256), 0, stream>>>(partials, nblocks, out, scale);
    }
}

// Round 5
// 142.213 us; speedup vs baseline: 1.2854x; 1.1182x over previous
//
#include <hip/hip_runtime.h>

typedef __attribute__((ext_vector_type(8))) __bf16 bf16x8;
typedef __attribute__((ext_vector_type(4))) float f32x4;
typedef __attribute__((ext_vector_type(8))) unsigned short ushort8;

#define DSAMP 512
#define DIM   128
#define REG5  16384                // one staged region: 128 rows * 128 B (bf16, swizzled)
#define NPAIR 18                   // paired tiles per batch (2 tiles per block)

// ---------------------------------------------------------------------------
// Single-pass fused kernel, v4. R4 lesson: at __launch_bounds__(256,3) the
// unified reg cap is 168 (observed 84 VGPR + 84 AGPR = exactly 168, with
// 62 B/thread of spill). The peak was p0..p7 (32) live across BOTH
// compute(1) AND tile_sum. v4 reorders tile 0 so the staged B chunk dies
// (WRITEB) before tile_sum runs: peak liveness ~153 <= 168, no spill.
// Everything else identical to v3.
// ---------------------------------------------------------------------------
__constant__ unsigned char T_Asrc[NPAIR]  = {0,0,0,0,0,0,0,0, 1,1,1,1,1,1,1,1,1,1};
__constant__ unsigned char T_Ai[NPAIR]    = {0,0,1,1,1,2,2,3, 0,0,0,0,1,1,1,2,2,3};
__constant__ unsigned char T_Bsrc0[NPAIR] = {0,0,0,0,1,0,1,0, 1,1,0,0,1,1,0,1,0,1};
__constant__ unsigned char T_Bsrc1[NPAIR] = {0,0,0,1,1,0,1,1, 1,1,0,0,1,0,0,1,0,0};
__constant__ unsigned char T_Bj0[NPAIR]   = {0,2,1,3,2,2,2,3, 0,2,0,2,1,3,2,2,0,3};
__constant__ unsigned char T_Bj1[NPAIR]   = {1,3,2,1,3,3,3,3, 1,3,1,3,2,0,3,3,3,0};
// weight codes: 0 -> +1.0 (xy), 1 -> -1.0 (xx/yy off-diag), 2 -> -0.5 (diag)
__constant__ char          T_wc0[NPAIR]   = {2,1,2,1,0,2,0,2, 2,1,0,0,2,1,0,2,0,2};
__constant__ char          T_wc1[NPAIR]   = {1,1,1,0,0,1,0,0, 1,1,0,0,1,0,0,1,0,0};
__constant__ unsigned char T_d0[NPAIR]    = {1,0,1,0,0,1,0,1, 1,0,0,0,1,0,0,1,0,1};

// arrayless fp32x8 -> bf16x8 RNE convert + sum of squares (all SSA values)
__device__ __forceinline__ ushort8 cvt8(float4 v0, float4 v1, float& ss) {
    ss = v0.x * v0.x + v0.y * v0.y + v0.z * v0.z + v0.w * v0.w
       + v1.x * v1.x + v1.y * v1.y + v1.z * v1.z + v1.w * v1.w;
    ushort8 hv;
    unsigned u;
    u = __float_as_uint(v0.x); hv[0] = (unsigned short)((u + 0x7fffu + ((u >> 16) & 1u)) >> 16);
    u = __float_as_uint(v0.y); hv[1] = (unsigned short)((u + 0x7fffu + ((u >> 16) & 1u)) >> 16);
    u = __float_as_uint(v0.z); hv[2] = (unsigned short)((u + 0x7fffu + ((u >> 16) & 1u)) >> 16);
    u = __float_as_uint(v0.w); hv[3] = (unsigned short)((u + 0x7fffu + ((u >> 16) & 1u)) >> 16);
    u = __float_as_uint(v1.x); hv[4] = (unsigned short)((u + 0x7fffu + ((u >> 16) & 1u)) >> 16);
    u = __float_as_uint(v1.y); hv[5] = (unsigned short)((u + 0x7fffu + ((u >> 16) & 1u)) >> 16);
    u = __float_as_uint(v1.z); hv[6] = (unsigned short)((u + 0x7fffu + ((u >> 16) & 1u)) >> 16);
    u = __float_as_uint(v1.w); hv[7] = (unsigned short)((u + 0x7fffu + ((u >> 16) & 1u)) >> 16);
    return hv;
}

// issue 8 global loads for one B chunk into NAMED registers p0..p7
#define LOADB(Bp, cc) do {                                                    \
    const float* gb_ = (Bp) + (size_t)rB * 128 + (cc) * 64 + jbB * 8;         \
    p0 = ((const float4*)gb_)[0];          p1 = ((const float4*)gb_)[1];      \
    p2 = ((const float4*)(gb_ + 4096))[0]; p3 = ((const float4*)(gb_ + 4096))[1]; \
    p4 = ((const float4*)(gb_ + 8192))[0]; p5 = ((const float4*)(gb_ + 8192))[1]; \
    p6 = ((const float4*)(gb_ +12288))[0]; p7 = ((const float4*)(gb_ +12288))[1]; \
} while (0)

#define RED8(sv) do {                       \
    sv += __shfl_down(sv, 4, 8);            \
    sv += __shfl_down(sv, 2, 8);            \
    sv += __shfl_down(sv, 1, 8);            \
} while (0)

// convert + ds_write the staged chunk, accumulate per-row norm partials
#define WRITEB(QnArr, add) do {                                               \
    float ssw_; ushort8 hw_;                                                  \
    hw_ = cvt8(p0, p1, ssw_); *(ushort8*)(dstB +     0) = hw_; RED8(ssw_);    \
    if ((tid & 7) == 0) { if (add) (QnArr)[rB]      += ssw_; else (QnArr)[rB]      = ssw_; } \
    hw_ = cvt8(p2, p3, ssw_); *(ushort8*)(dstB +  4096) = hw_; RED8(ssw_);    \
    if ((tid & 7) == 0) { if (add) (QnArr)[rB + 32] += ssw_; else (QnArr)[rB + 32] = ssw_; } \
    hw_ = cvt8(p4, p5, ssw_); *(ushort8*)(dstB +  8192) = hw_; RED8(ssw_);    \
    if ((tid & 7) == 0) { if (add) (QnArr)[rB + 64] += ssw_; else (QnArr)[rB + 64] = ssw_; } \
    hw_ = cvt8(p6, p7, ssw_); *(ushort8*)(dstB + 12288) = hw_; RED8(ssw_);    \
    if ((tid & 7) == 0) { if (add) (QnArr)[rB + 96] += ssw_; else (QnArr)[rB + 96] = ssw_; } \
} while (0)

__global__ __launch_bounds__(256, 3)
void mmd_fused(const float* __restrict__ x, const float* __restrict__ y,
               float* __restrict__ partials) {
    __shared__ __align__(16) char smem[3 * REG5];   // A c0 | A c1 | B (49152 B)
    __shared__ float Pn[128];
    __shared__ float Qn0[128];
    __shared__ float Qn1[128];
    __shared__ float wred[4];

    const int tid = threadIdx.x;
    const int bid = blockIdx.x;
    const int xcd = bid & 7;
    const int seq = bid >> 3;            // 0..287
    const int s   = seq % NPAIR;
    const int grp = seq / NPAIR;         // 0..15
    const int b   = xcd + 8 * grp;       // batch; all 18 pair-blocks adjacent

    const int Ai  = T_Ai[s];
    const int Bj0 = T_Bj0[s];
    const int Bj1 = T_Bj1[s];
    const float* Asrc  = T_Asrc[s]  ? y : x;
    const float* B0src = T_Bsrc0[s] ? y : x;
    const float* B1src = T_Bsrc1[s] ? y : x;
    const int wc0 = T_wc0[s], wc1 = T_wc1[s];
    const float w0 = (wc0 == 0) ? 1.0f : ((wc0 == 1) ? -1.0f : -0.5f);
    const float w1 = (wc1 == 0) ? 1.0f : ((wc1 == 1) ? -1.0f : -0.5f);
    const bool dg0 = T_d0[s] != 0;

    const size_t rowbase = (size_t)b * 512;
    const float* Ap  = Asrc  + (rowbase + (size_t)Ai  * 128) * 128;
    const float* Bp0 = B0src + (rowbase + (size_t)Bj0 * 128) * 128;
    const float* Bp1 = B1src + (rowbase + (size_t)Bj1 * 128) * 128;

    const int lane    = tid & 63;
    const int wv      = tid >> 6;
    const int rowHalf = (wv >> 1) * 64;
    const int colHalf = (wv & 1) * 64;
    const int fm      = lane & 15;
    const int kq      = lane >> 4;
    const int sw      = fm & 7;

    // B staging thread map: 8 lanes per row, 32 row-quads
    const int jbB = tid & 7;
    const int rB  = tid >> 3;            // 0..31
    char* dstB = smem + 2 * REG5 + rB * 128 + ((jbB ^ (rB & 7)) * 16);

    float4 p0, p1, p2, p3, p4, p5, p6, p7;   // the ONE in-flight B chunk

    f32x4 acc[4][4];
    auto zero_acc = [&]() {
        #pragma unroll
        for (int a2 = 0; a2 < 4; ++a2)
            #pragma unroll
            for (int b2 = 0; b2 < 4; ++b2)
                acc[a2][b2] = (f32x4){0.f, 0.f, 0.f, 0.f};
    };

    auto compute = [&](int creg) {
        const char* Ab = smem + creg * REG5;
        const char* Bb = smem + 2 * REG5;
        #pragma unroll
        for (int ks = 0; ks < 2; ++ks) {
            const int jx = ((ks * 4 + kq) ^ sw) * 16;
            bf16x8 ah[4], bh[4];
            #pragma unroll
            for (int a2 = 0; a2 < 4; ++a2)
                ah[a2] = *(const bf16x8*)(Ab + (rowHalf + a2 * 16 + fm) * 128 + jx);
            #pragma unroll
            for (int b2 = 0; b2 < 4; ++b2)
                bh[b2] = *(const bf16x8*)(Bb + (colHalf + b2 * 16 + fm) * 128 + jx);
            __builtin_amdgcn_s_setprio(1);
            #pragma unroll
            for (int a2 = 0; a2 < 4; ++a2)
                #pragma unroll
                for (int b2 = 0; b2 < 4; ++b2)
                    acc[a2][b2] = __builtin_amdgcn_mfma_f32_16x16x32_bf16(
                        ah[a2], bh[b2], acc[a2][b2], 0, 0, 0);
            __builtin_amdgcn_s_setprio(0);
        }
    };

    auto tile_sum = [&](const float* Qn, bool dg) -> float {
        float Pr[16], Qc[4];
        #pragma unroll
        for (int a2 = 0; a2 < 4; ++a2)
            #pragma unroll
            for (int rg2 = 0; rg2 < 4; ++rg2)
                Pr[a2 * 4 + rg2] = Pn[rowHalf + a2 * 16 + kq * 4 + rg2];
        #pragma unroll
        for (int b2 = 0; b2 < 4; ++b2) Qc[b2] = Qn[colHalf + b2 * 16 + fm];
        float ls = 0.f;
        if (dg) {
            #pragma unroll
            for (int a2 = 0; a2 < 4; ++a2)
                #pragma unroll
                for (int b2 = 0; b2 < 4; ++b2)
                    #pragma unroll
                    for (int rg2 = 0; rg2 < 4; ++rg2) {
                        float d2 = fmaf(-2.0f, acc[a2][b2][rg2], Pr[a2 * 4 + rg2] + Qc[b2]);
                        float v  = __builtin_amdgcn_sqrtf(fmaxf(d2, 0.0f));
                        if ((rowHalf + a2 * 16 + kq * 4 + rg2) == (colHalf + b2 * 16 + fm)) v = 0.f;
                        ls += v;
                    }
        } else {
            #pragma unroll
            for (int a2 = 0; a2 < 4; ++a2)
                #pragma unroll
                for (int b2 = 0; b2 < 4; ++b2)
                    #pragma unroll
                    for (int rg2 = 0; rg2 < 4; ++rg2) {
                        float d2 = fmaf(-2.0f, acc[a2][b2][rg2], Pr[a2 * 4 + rg2] + Qc[b2]);
                        ls += __builtin_amdgcn_sqrtf(fmaxf(d2, 0.0f));
                    }
        }
        return ls;
    };

    // ---- phase S: B0c0 issue-early into p0..p7, A streamed slice-by-slice ----
    LOADB(Bp0, 0);                         // latency hidden under A streaming
    #pragma unroll
    for (int it = 0; it < 8; ++it) {
        int u  = it * 256 + tid;           // (row, c, jb)
        int jb = u & 7;
        int cc = (u >> 3) & 1;
        int r  = u >> 4;
        const float* g = Ap + (size_t)r * 128 + cc * 64 + jb * 8;
        float4 v0 = ((const float4*)g)[0];
        float4 v1 = ((const float4*)g)[1];
        float ss;
        ushort8 hv = cvt8(v0, v1, ss);
        *(ushort8*)(smem + cc * REG5 + r * 128 + ((jb ^ (r & 7)) * 16)) = hv;
        // full-row norm: 16 lanes = (c0 jb0..7, c1 jb0..7)
        ss += __shfl_down(ss, 8, 16);
        ss += __shfl_down(ss, 4, 16);
        ss += __shfl_down(ss, 2, 16);
        ss += __shfl_down(ss, 1, 16);
        if ((tid & 15) == 0) Pn[r] = ss;
    }
    WRITEB(Qn0, false);                    // p0..p7 die here
    __syncthreads();                       // A + B(t0,c0) staged

    // ---- tile 0 ----
    zero_acc();
    LOADB(Bp0, 1);                         // issue-early: latency under compute
    compute(0);
    __syncthreads();                       // B buf free
    WRITEB(Qn0, true);                     // Qn0 complete; p dies
    __syncthreads();                       // B(t0,c1) staged
    LOADB(Bp1, 0);
    compute(1);
    __syncthreads();                       // B buf free (all waves done reading)
    WRITEB(Qn1, false);                    // p dies BEFORE tile_sum (the v4 fix)
    float lsum = w0 * tile_sum(Qn0, dg0);  // acc + Pr/Qc only: ~110 regs live
    zero_acc();
    __syncthreads();                       // B(t1,c0) staged

    // ---- tile 1 ----
    LOADB(Bp1, 1);
    compute(0);
    __syncthreads();                       // B buf free
    WRITEB(Qn1, true);                     // Qn1 complete; p dies
    __syncthreads();                       // B(t1,c1) staged
    compute(1);
    lsum += w1 * tile_sum(Qn1, false);

    #pragma unroll
    for (int off = 32; off > 0; off >>= 1) lsum += __shfl_down(lsum, off, 64);
    if (lane == 0) wred[wv] = lsum;
    __syncthreads();
    if (tid == 0)
        partials[bid] = wred[0] + wred[1] + wred[2] + wred[3];
}

// ---------------------------------------------------------------------------
// Fallback (in-kernel 3-term conversion, full 48 tiles/batch) if B != 128.
// ---------------------------------------------------------------------------
__global__ __launch_bounds__(256, 2)
void mmd_tile_fallback(const float* __restrict__ x, const float* __restrict__ y,
                       float* __restrict__ partials) {
    __shared__ __align__(16) char smem[4 * 128 * 144];
    __shared__ float Pn[128];
    __shared__ float Qn[128];
    __shared__ float wred[4];

    char* Ah = smem;
    char* Al = smem + 1 * 128 * 144;
    char* Bh = smem + 2 * 128 * 144;
    char* Bl = smem + 3 * 128 * 144;

    const int tid  = threadIdx.x;
    const int bid  = blockIdx.x;
    const int tj   = bid & 3;
    const int ti   = (bid >> 2) & 3;
    const int type = (bid >> 4) % 3;
    const int b    = bid / 48;

    const float* Xb = x + (size_t)b * DSAMP * DIM;
    const float* Yb = y + (size_t)b * DSAMP * DIM;
    const float* Pp; const float* Qp; float w;
    if (type == 0)      { Pp = Xb; Qp = Yb; w = 1.0f;  }
    else if (type == 1) { Pp = Xb; Qp = Xb; w = -0.5f; }
    else                { Pp = Yb; Qp = Yb; w = -0.5f; }
    Pp += (size_t)ti * 128 * DIM;
    Qp += (size_t)tj * 128 * DIM;

    {
        const float* rp = (tid < 128) ? (Pp + (size_t)tid * DIM)
                                      : (Qp + (size_t)(tid - 128) * DIM);
        float s = 0.f;
        #pragma unroll
        for (int k4 = 0; k4 < 32; ++k4) {
            float4 v = ((const float4*)rp)[k4];
            s += v.x * v.x + v.y * v.y + v.z * v.z + v.w * v.w;
        }
        if (tid < 128) Pn[tid] = s; else Qn[tid - 128] = s;
    }

    const int lane    = tid & 63;
    const int wv      = tid >> 6;
    const int rowHalf = (wv >> 1) * 64;
    const int colHalf = (wv & 1) * 64;
    const int fm      = lane & 15;
    const int kq      = lane >> 4;

    f32x4 acc[4][4];
    #pragma unroll
    for (int a2 = 0; a2 < 4; ++a2)
        #pragma unroll
        for (int b2 = 0; b2 < 4; ++b2)
            acc[a2][b2] = (f32x4){0.f, 0.f, 0.f, 0.f};

    for (int c = 0; c < 2; ++c) {
        if (c) __syncthreads();
        #pragma unroll
        for (int side = 0; side < 2; ++side) {
            const float* sp = side ? Qp : Pp;
            char* dh = side ? Bh : Ah;
            char* dl = side ? Bl : Al;
            #pragma unroll
            for (int it = 0; it < 4; ++it) {
                int u  = it * 256 + tid;
                int r  = u >> 3;
                int c8 = u & 7;
                const float* g = sp + (size_t)r * DIM + c * 64 + c8 * 8;
                float4 v0 = ((const float4*)g)[0];
                float4 v1 = ((const float4*)g)[1];
                float xs[8] = {v0.x, v0.y, v0.z, v0.w, v1.x, v1.y, v1.z, v1.w};
                ushort8 hv, lv;
                #pragma unroll
                for (int e = 0; e < 8; ++e) {
                    float xv = xs[e];
                    unsigned ub = __float_as_uint(xv);
                    unsigned hr = (ub + 0x7fffu + ((ub >> 16) & 1u)) >> 16;
                    float hf = __uint_as_float(hr << 16);
                    float rs = xv - hf;
                    unsigned ul = __float_as_uint(rs);
                    unsigned lr = (ul + 0x7fffu + ((ul >> 16) & 1u)) >> 16;
                    hv[e] = (unsigned short)hr;
                    lv[e] = (unsigned short)lr;
                }
                *(ushort8*)(dh + r * 144 + c8 * 16) = hv;
                *(ushort8*)(dl + r * 144 + c8 * 16) = lv;
            }
        }
        __syncthreads();
        #pragma unroll
        for (int ks = 0; ks < 2; ++ks) {
            const int kb2 = (ks * 32 + kq * 8) * 2;
            bf16x8 ah[4], al[4], bh[4], bl[4];
            #pragma unroll
            for (int a2 = 0; a2 < 4; ++a2) {
                int ar = rowHalf + a2 * 16 + fm;
                ah[a2] = *(const bf16x8*)(Ah + ar * 144 + kb2);
                al[a2] = *(const bf16x8*)(Al + ar * 144 + kb2);
            }
            #pragma unroll
            for (int b2 = 0; b2 < 4; ++b2) {
                int br = colHalf + b2 * 16 + fm;
                bh[b2] = *(const bf16x8*)(Bh + br * 144 + kb2);
                bl[b2] = *(const bf16x8*)(Bl + br * 144 + kb2);
            }
            #pragma unroll
            for (int a2 = 0; a2 < 4; ++a2)
                #pragma unroll
                for (int b2 = 0; b2 < 4; ++b2) {
                    acc[a2][b2] = __builtin_amdgcn_mfma_f32_16x16x32_bf16(ah[a2], bh[b2], acc[a2][b2], 0, 0, 0);
                    acc[a2][b2] = __builtin_amdgcn_mfma_f32_16x16x32_bf16(ah[a2], bl[b2], acc[a2][b2], 0, 0, 0);
                    acc[a2][b2] = __builtin_amdgcn_mfma_f32_16x16x32_bf16(al[a2], bh[b2], acc[a2][b2], 0, 0, 0);
                }
        }
    }

    const bool selfm = (type != 0) && (ti == tj);
    float lsum = 0.f;
    #pragma unroll
    for (int a2 = 0; a2 < 4; ++a2) {
        int ib = rowHalf + a2 * 16 + kq * 4;
        #pragma unroll
        for (int b2 = 0; b2 < 4; ++b2) {
            int j = colHalf + b2 * 16 + fm;
            float qn = Qn[j];
            #pragma unroll
            for (int rg = 0; rg < 4; ++rg) {
                int i = ib + rg;
                float d2 = Pn[i] + qn - 2.0f * acc[a2][b2][rg];
                if (d2 > 0.f && !(selfm && i == j)) lsum += sqrtf(d2);
            }
        }
    }
    #pragma unroll
    for (int off = 32; off > 0; off >>= 1) lsum += __shfl_down(lsum, off, 64);
    if (lane == 0) wred[wv] = lsum;
    __syncthreads();
    if (tid == 0)
        partials[bid] = (wred[0] + wred[1] + wred[2] + wred[3]) * w;
}

__global__ __launch_bounds__(256)
void mmd_finalize_kernel(const float* __restrict__ partials, int n,
                         float* __restrict__ out, double scale) {
    __shared__ double sh[256];
    double s = 0.0;
    for (int i = threadIdx.x; i < n; i += 256) s += (double)partials[i];
    sh[threadIdx.x] = s;
    __syncthreads();
    for (int off = 128; off > 0; off >>= 1) {
        if ((int)threadIdx.x < off) sh[threadIdx.x] += sh[threadIdx.x + off];
        __syncthreads();
    }
    if (threadIdx.x == 0) out[0] = (float)(sh[0] * scale);
}

extern "C" void kernel_launch(void* const* d_in, const int* in_sizes, int n_in,
                              void* d_out, int out_size, void* d_ws, size_t ws_size,
                              hipStream_t stream) {
    const float* x = (const float*)d_in[0];
    const float* y = (const float*)d_in[1];
    float* out = (float*)d_out;

    const int n = in_sizes[0];
    const int B = n / (DSAMP * DIM);       // 128
    const double scale = 1.0 / ((double)B * (double)DSAMP * (double)DSAMP);

    float* partials = (float*)d_ws;
    if (B == 128 && ws_size >= (size_t)(128 * NPAIR) * 4) {
        const int nblocks = 128 * NPAIR;   // 2304 = 3.0 exact rounds @ 3 blk/CU
        mmd_fused<<<dim3(nblocks), dim3(256), 0, stream>>>(x, y, partials);
        mmd_finalize_kernel<<<dim3(1), dim3(256), 0, stream>>>(partials, nblocks, out, scale);
    } else {
        const int nblocks = B * 48;
        mmd_tile_fallback<<<dim3(nblocks), dim3(256), 0, stream>>>(x, y, partials);
        mmd_finalize_kernel<<<dim3(1), dim3(256), 0, stream>>>(partials, nblocks, out, scale);
    }
}